// Round 14
// baseline (152.073 us; speedup 1.0000x reference)
//
#include <hip/hip_runtime.h>
#include <hip/hip_bf16.h>

#define HIDF 96
#define INF 256
#define BK_SHIFT 5
#define BK_SIZE 32         // dst nodes per bucket
#define SCAT_NB 512        // blocks in hist/scatter pass (must match between them)
#define MAX_BKT_E 1536     // bucket edge capacity (mean ~512, huge sigma headroom)

typedef short bf16x8 __attribute__((ext_vector_type(8)));
typedef float f32x4 __attribute__((ext_vector_type(4)));

static __device__ inline short f2bf(float f) {
    __hip_bfloat16 b = __float2bfloat16(f);
    short s;
    __builtin_memcpy(&s, &b, 2);
    return s;
}
static __device__ inline float bf2f(unsigned u) {
    union { unsigned x; float f; } v;
    v.x = u << 16;
    return v.f;
}

// ---------- pack W_lin and W_fc into MFMA B-fragment layout (R4-proven) ----------
__global__ __launch_bounds__(256) void pack_weights(
    const float* __restrict__ W_lin, const float* __restrict__ W_fc,
    short* __restrict__ Bp1, short* __restrict__ Bp2)
{
    int t = blockIdx.x * 256 + threadIdx.x;
    if (t < 8 * 6 * 64) {
        int kt = t / (6 * 64), rem = t % (6 * 64), nt = rem / 64, l = rem % 64;
        int n = nt * 16 + (l & 15);
        int k0 = kt * 32 + ((l >> 4) << 3);
        short v[8];
        #pragma unroll
        for (int j = 0; j < 8; ++j) v[j] = f2bf(W_lin[n * INF + k0 + j]);
        #pragma unroll
        for (int j = 0; j < 8; ++j) Bp1[(size_t)t * 8 + j] = v[j];
    } else if (t < 8 * 6 * 64 + 3 * 6 * 64) {
        int u = t - 8 * 6 * 64;
        int kt = u / (6 * 64), rem = u % (6 * 64), nt = rem / 64, l = rem % 64;
        int n = nt * 16 + (l & 15);
        int k0 = kt * 32 + ((l >> 4) << 3);
        short v[8];
        #pragma unroll
        for (int j = 0; j < 8; ++j) v[j] = f2bf(W_fc[n * HIDF + k0 + j]);
        #pragma unroll
        for (int j = 0; j < 8; ++j) Bp2[(size_t)u * 8 + j] = v[j];
    }
}

// ---------- pass 1: per-block bucket histogram (LDS atomics only) ----------
__global__ __launch_bounds__(256) void bucket_hist(
    const int* __restrict__ dst1, const int* __restrict__ dst2,
    int* __restrict__ hist_mat, int E, int nb1, int nbkt)
{
    __shared__ int lh[4096];                 // nbkt = 3126 fits
    for (int i = threadIdx.x; i < nbkt; i += 256) lh[i] = 0;
    __syncthreads();
    int epb = (2 * E + SCAT_NB - 1) / SCAT_NB;
    int s0 = blockIdx.x * epb;
    int s1 = min(s0 + epb, 2 * E);
    for (int e = s0 + threadIdx.x; e < s1; e += 256) {
        int b;
        if (e < E) b = dst1[e] >> BK_SHIFT;
        else       b = nb1 + (dst2[e - E] >> BK_SHIFT);
        atomicAdd(&lh[b], 1);
    }
    __syncthreads();
    for (int i = threadIdx.x; i < nbkt; i += 256)
        hist_mat[(size_t)i * SCAT_NB + blockIdx.x] = lh[i];
}

// ---------- scan: 2048 elems/block, in-place exclusive ----------
__global__ __launch_bounds__(256) void scan_part8(
    int* __restrict__ data, int* __restrict__ bsum, int n)
{
    __shared__ int s[256];
    int base = blockIdx.x * 2048 + threadIdx.x * 8;
    int v[8]; int tot = 0;
    #pragma unroll
    for (int j = 0; j < 8; ++j) {
        v[j] = (base + j < n) ? data[base + j] : 0;
        tot += v[j];
    }
    s[threadIdx.x] = tot;
    __syncthreads();
    for (int d = 1; d < 256; d <<= 1) {
        int t = (threadIdx.x >= d) ? s[threadIdx.x - d] : 0;
        __syncthreads();
        s[threadIdx.x] += t;
        __syncthreads();
    }
    int pre = s[threadIdx.x] - tot;
    #pragma unroll
    for (int j = 0; j < 8; ++j) {
        if (base + j < n) data[base + j] = pre;
        pre += v[j];
    }
    if (threadIdx.x == 255) bsum[blockIdx.x] = s[255];
}

__global__ __launch_bounds__(1024) void scan_top(int* __restrict__ bsum, int nb)
{
    __shared__ int s[1024];
    int i = threadIdx.x;
    int v = (i < nb) ? bsum[i] : 0;
    s[i] = v;
    __syncthreads();
    for (int d = 1; d < 1024; d <<= 1) {
        int t = (i >= d) ? s[i - d] : 0;
        __syncthreads();
        s[i] += t;
        __syncthreads();
    }
    if (i < nb) bsum[i] = s[i] - v;
}

__global__ __launch_bounds__(256) void scan_add8(
    int* __restrict__ data, const int* __restrict__ bsum, int n)
{
    int base = blockIdx.x * 2048 + threadIdx.x * 8;
    int add = bsum[blockIdx.x];
    #pragma unroll
    for (int j = 0; j < 8; ++j)
        if (base + j < n) data[base + j] += add;
}

// ---------- pass 2: scatter edges into bucket-grouped payload (LDS cursors) ----------
__global__ __launch_bounds__(256) void bucket_scatter(
    const int* __restrict__ src1, const int* __restrict__ dst1,
    const int* __restrict__ src2, const int* __restrict__ dst2,
    const int* __restrict__ hist_mat, int* __restrict__ payload,
    int E, int nb1, int nbkt)
{
    __shared__ int lcur[4096];
    for (int i = threadIdx.x; i < nbkt; i += 256)
        lcur[i] = hist_mat[(size_t)i * SCAT_NB + blockIdx.x];
    __syncthreads();
    int epb = (2 * E + SCAT_NB - 1) / SCAT_NB;
    int s0 = blockIdx.x * epb;
    int s1 = min(s0 + epb, 2 * E);
    for (int e = s0 + threadIdx.x; e < s1; e += 256) {
        int s, d, b;
        if (e < E) { s = src1[e]; d = dst1[e]; b = d >> BK_SHIFT; }
        else       { int e2 = e - E; s = src2[e2]; d = dst2[e2]; b = nb1 + (d >> BK_SHIFT); }
        int slot = atomicAdd(&lcur[b], 1);   // LDS atomic, cheap
        payload[slot] = ((d & (BK_SIZE - 1)) << 16) | s;   // src < 65536
    }
}

// ---------- GEMM1: K-split staging (R10-proven, unified linb) ----------
__global__ __launch_bounds__(256) void gemm_lin(
    const float* __restrict__ h, const short* __restrict__ Bp1,
    const float* __restrict__ b_lin, const float* __restrict__ W_al,
    const float* __restrict__ b_al,
    unsigned short* __restrict__ linb, float* __restrict__ ai, int N)
{
    __shared__ short Bs[4 * 6 * 64 * 8];   // 24 KiB (half the ktiles at a time)

    int lane = threadIdx.x & 63;
    int wid = threadIdx.x >> 6;
    int m0 = blockIdx.x * 64 + wid * 16;
    int arow = m0 + (lane & 15);
    int rc = arow < N ? arow : N - 1;
    const float* hrow = h + (size_t)rc * INF;
    int koff = (lane >> 4) << 3;

    f32x4 acc[6];
    #pragma unroll
    for (int nt = 0; nt < 6; ++nt) acc[nt] = (f32x4){0.f, 0.f, 0.f, 0.f};

    for (int half = 0; half < 2; ++half) {
        {
            const uint4* gsrc = reinterpret_cast<const uint4*>(Bp1) + (size_t)half * (4 * 6 * 64 * 8 / 8);
            uint4* ldst = reinterpret_cast<uint4*>(Bs);
            for (int i = threadIdx.x; i < 4 * 6 * 64 * 8 / 8; i += 256) ldst[i] = gsrc[i];
        }
        __syncthreads();

        #pragma unroll
        for (int kt = 0; kt < 4; ++kt) {
            int ktg = half * 4 + kt;
            const float4* hp = reinterpret_cast<const float4*>(hrow + ktg * 32 + koff);
            float4 f0 = hp[0], f1 = hp[1];
            bf16x8 a8;
            a8[0] = f2bf(f0.x); a8[1] = f2bf(f0.y); a8[2] = f2bf(f0.z); a8[3] = f2bf(f0.w);
            a8[4] = f2bf(f1.x); a8[5] = f2bf(f1.y); a8[6] = f2bf(f1.z); a8[7] = f2bf(f1.w);
            #pragma unroll
            for (int nt = 0; nt < 6; ++nt) {
                bf16x8 b8 = *reinterpret_cast<const bf16x8*>(&Bs[((kt * 6 + nt) * 64 + lane) * 8]);
                acc[nt] = __builtin_amdgcn_mfma_f32_16x16x32_bf16(a8, b8, acc[nt], 0, 0, 0);
            }
        }
        __syncthreads();
    }

    float pai[4] = {0.f, 0.f, 0.f, 0.f};
    int rbase = m0 + ((lane >> 4) << 2);
    #pragma unroll
    for (int nt = 0; nt < 6; ++nt) {
        int col = nt * 16 + (lane & 15);
        float bl = b_lin[col];
        float wal = W_al[col];
        #pragma unroll
        for (int r = 0; r < 4; ++r) {
            float v = acc[nt][r] + bl;
            int rrow = rbase + r;
            if (rrow < N) linb[(size_t)rrow * HIDF + col] = (unsigned short)f2bf(v);
            pai[r] = fmaf(wal, v, pai[r]);
        }
    }
    #pragma unroll
    for (int r = 0; r < 4; ++r) {
        float p = pai[r];
        p += __shfl_xor(p, 1);
        p += __shfl_xor(p, 2);
        p += __shfl_xor(p, 4);
        p += __shfl_xor(p, 8);
        int rrow = rbase + r;
        if ((lane & 15) == 0 && rrow < N) ai[rrow] = p + b_al[0];
    }
}

// ---------- agg+comb fused (BK=32): block b reduces bucket b (graph1) AND bucket nb1+b (graph2)
//            into LDS bf16 tiles, then runs the attention-combine in-block ----------
__global__ __launch_bounds__(256) void agg_comb(
    const unsigned short* __restrict__ linb,
    const float* __restrict__ norm1, const float* __restrict__ norm2,
    const float* __restrict__ ai,
    const float* __restrict__ W_ar, const float* __restrict__ b_ar,
    const int* __restrict__ hist_mat, const int* __restrict__ payload,
    unsigned short* __restrict__ combb,
    int N, int nb1, int nbkt, int totE)
{
    __shared__ unsigned short srt[MAX_BKT_E];       // 3 KiB, reused across the two graphs
    __shared__ int scn[BK_SIZE];
    __shared__ int sstart[BK_SIZE + 1];
    __shared__ int cur[BK_SIZE];
    __shared__ unsigned short Cs[2][BK_SIZE][104];  // 13.3 KiB bf16 acc tiles

    int b = blockIdx.x;
    int node0 = b << BK_SHIFT;

    for (int gph = 0; gph < 2; ++gph) {
        int bidx = gph * nb1 + b;
        int start = hist_mat[(size_t)bidx * SCAT_NB];
        int end = (bidx == nbkt - 1) ? totE : hist_mat[(size_t)(bidx + 1) * SCAT_NB];
        if (end - start > MAX_BKT_E) end = start + MAX_BKT_E;   // safety clamp
        int ne = end - start;

        __syncthreads();   // protect srt/scn reuse from previous phase's readers
        if (threadIdx.x < BK_SIZE) scn[threadIdx.x] = 0;
        __syncthreads();

        // count per dst-local
        for (int k = start + threadIdx.x; k < end; k += 256)
            atomicAdd(&scn[payload[k] >> 16], 1);
        __syncthreads();

        // inclusive Hillis-Steele scan over 32 counters
        int v = (threadIdx.x < BK_SIZE) ? scn[threadIdx.x] : 0;
        for (int d = 1; d < BK_SIZE; d <<= 1) {
            int t = 0;
            if (threadIdx.x < BK_SIZE && threadIdx.x >= d) t = scn[threadIdx.x - d];
            __syncthreads();
            if (threadIdx.x < BK_SIZE) scn[threadIdx.x] += t;
            __syncthreads();
        }
        if (threadIdx.x < BK_SIZE) {
            int excl = scn[threadIdx.x] - v;
            sstart[threadIdx.x] = excl;
            cur[threadIdx.x] = excl;
        }
        if (threadIdx.x == 0) sstart[BK_SIZE] = ne;
        __syncthreads();

        // scatter srcs into dst-sorted LDS array
        for (int k = start + threadIdx.x; k < end; k += 256) {
            int pl = payload[k];
            int slot = atomicAdd(&cur[pl >> 16], 1);
            srt[slot] = (unsigned short)(pl & 0xffff);
        }
        __syncthreads();

        // segment reduction: 21 groups of 12 lanes, register accumulation, 4-deep gather ILP
        const float* nrm = gph ? norm2 : norm1;
        int g = threadIdx.x / 12;
        int c = threadIdx.x % 12;
        if (g < 21) {
            for (int dl = g; dl < BK_SIZE; dl += 21) {
                int node = node0 + dl;
                if (node >= N) break;
                int s0 = sstart[dl], s1 = sstart[dl + 1];
                float a[8];
                #pragma unroll
                for (int j = 0; j < 8; ++j) a[j] = 0.f;
                int k = s0;
                for (; k + 3 < s1; k += 4) {
                    int sA = srt[k], sB = srt[k + 1], sC = srt[k + 2], sD = srt[k + 3];
                    float nvA = nrm[sA], nvB = nrm[sB], nvC = nrm[sC], nvD = nrm[sD];
                    uint4 rA = *reinterpret_cast<const uint4*>(linb + (size_t)sA * HIDF + c * 8);
                    uint4 rB = *reinterpret_cast<const uint4*>(linb + (size_t)sB * HIDF + c * 8);
                    uint4 rC = *reinterpret_cast<const uint4*>(linb + (size_t)sC * HIDF + c * 8);
                    uint4 rD = *reinterpret_cast<const uint4*>(linb + (size_t)sD * HIDF + c * 8);
                    a[0] = fmaf(bf2f(rA.x & 0xffffu), nvA, a[0]);
                    a[1] = fmaf(bf2f(rA.x >> 16),     nvA, a[1]);
                    a[2] = fmaf(bf2f(rA.y & 0xffffu), nvA, a[2]);
                    a[3] = fmaf(bf2f(rA.y >> 16),     nvA, a[3]);
                    a[4] = fmaf(bf2f(rA.z & 0xffffu), nvA, a[4]);
                    a[5] = fmaf(bf2f(rA.z >> 16),     nvA, a[5]);
                    a[6] = fmaf(bf2f(rA.w & 0xffffu), nvA, a[6]);
                    a[7] = fmaf(bf2f(rA.w >> 16),     nvA, a[7]);
                    a[0] = fmaf(bf2f(rB.x & 0xffffu), nvB, a[0]);
                    a[1] = fmaf(bf2f(rB.x >> 16),     nvB, a[1]);
                    a[2] = fmaf(bf2f(rB.y & 0xffffu), nvB, a[2]);
                    a[3] = fmaf(bf2f(rB.y >> 16),     nvB, a[3]);
                    a[4] = fmaf(bf2f(rB.z & 0xffffu), nvB, a[4]);
                    a[5] = fmaf(bf2f(rB.z >> 16),     nvB, a[5]);
                    a[6] = fmaf(bf2f(rB.w & 0xffffu), nvB, a[6]);
                    a[7] = fmaf(bf2f(rB.w >> 16),     nvB, a[7]);
                    a[0] = fmaf(bf2f(rC.x & 0xffffu), nvC, a[0]);
                    a[1] = fmaf(bf2f(rC.x >> 16),     nvC, a[1]);
                    a[2] = fmaf(bf2f(rC.y & 0xffffu), nvC, a[2]);
                    a[3] = fmaf(bf2f(rC.y >> 16),     nvC, a[3]);
                    a[4] = fmaf(bf2f(rC.z & 0xffffu), nvC, a[4]);
                    a[5] = fmaf(bf2f(rC.z >> 16),     nvC, a[5]);
                    a[6] = fmaf(bf2f(rC.w & 0xffffu), nvC, a[6]);
                    a[7] = fmaf(bf2f(rC.w >> 16),     nvC, a[7]);
                    a[0] = fmaf(bf2f(rD.x & 0xffffu), nvD, a[0]);
                    a[1] = fmaf(bf2f(rD.x >> 16),     nvD, a[1]);
                    a[2] = fmaf(bf2f(rD.y & 0xffffu), nvD, a[2]);
                    a[3] = fmaf(bf2f(rD.y >> 16),     nvD, a[3]);
                    a[4] = fmaf(bf2f(rD.z & 0xffffu), nvD, a[4]);
                    a[5] = fmaf(bf2f(rD.z >> 16),     nvD, a[5]);
                    a[6] = fmaf(bf2f(rD.w & 0xffffu), nvD, a[6]);
                    a[7] = fmaf(bf2f(rD.w >> 16),     nvD, a[7]);
                }
                for (; k < s1; ++k) {
                    int s = srt[k];
                    float nv = nrm[s];
                    uint4 raw = *reinterpret_cast<const uint4*>(linb + (size_t)s * HIDF + c * 8);
                    a[0] = fmaf(bf2f(raw.x & 0xffffu), nv, a[0]);
                    a[1] = fmaf(bf2f(raw.x >> 16),     nv, a[1]);
                    a[2] = fmaf(bf2f(raw.y & 0xffffu), nv, a[2]);
                    a[3] = fmaf(bf2f(raw.y >> 16),     nv, a[3]);
                    a[4] = fmaf(bf2f(raw.z & 0xffffu), nv, a[4]);
                    a[5] = fmaf(bf2f(raw.z >> 16),     nv, a[5]);
                    a[6] = fmaf(bf2f(raw.w & 0xffffu), nv, a[6]);
                    a[7] = fmaf(bf2f(raw.w >> 16),     nv, a[7]);
                }
                unsigned ob[4];
                ob[0] = ((unsigned)(unsigned short)f2bf(a[1]) << 16) | (unsigned short)f2bf(a[0]);
                ob[1] = ((unsigned)(unsigned short)f2bf(a[3]) << 16) | (unsigned short)f2bf(a[2]);
                ob[2] = ((unsigned)(unsigned short)f2bf(a[5]) << 16) | (unsigned short)f2bf(a[4]);
                ob[3] = ((unsigned)(unsigned short)f2bf(a[7]) << 16) | (unsigned short)f2bf(a[6]);
                uint4 ov; ov.x = ob[0]; ov.y = ob[1]; ov.z = ob[2]; ov.w = ob[3];
                *reinterpret_cast<uint4*>(&Cs[gph][dl][c * 8]) = ov;
            }
        }
    }
    __syncthreads();

    // ---- comb phase (R12 comb_c1 logic, sourced from LDS tiles): 4 threads per node ----
    int nl = threadIdx.x >> 2, q = threadIdx.x & 3;
    if (nl >= BK_SIZE) return;
    int n = node0 + nl;
    if (n >= N) return;

    const uint4* r1 = reinterpret_cast<const uint4*>(&Cs[0][nl][q * 24]);
    const uint4* r2 = reinterpret_cast<const uint4*>(&Cs[1][nl][q * 24]);
    float v1[24], v2[24];
    #pragma unroll
    for (int u = 0; u < 3; ++u) {
        uint4 a = r1[u], bb = r2[u];
        v1[u*8+0] = bf2f(a.x & 0xffffu); v1[u*8+1] = bf2f(a.x >> 16);
        v1[u*8+2] = bf2f(a.y & 0xffffu); v1[u*8+3] = bf2f(a.y >> 16);
        v1[u*8+4] = bf2f(a.z & 0xffffu); v1[u*8+5] = bf2f(a.z >> 16);
        v1[u*8+6] = bf2f(a.w & 0xffffu); v1[u*8+7] = bf2f(a.w >> 16);
        v2[u*8+0] = bf2f(bb.x & 0xffffu); v2[u*8+1] = bf2f(bb.x >> 16);
        v2[u*8+2] = bf2f(bb.y & 0xffffu); v2[u*8+3] = bf2f(bb.y >> 16);
        v2[u*8+4] = bf2f(bb.z & 0xffffu); v2[u*8+5] = bf2f(bb.z >> 16);
        v2[u*8+6] = bf2f(bb.w & 0xffffu); v2[u*8+7] = bf2f(bb.w >> 16);
    }

    float d1 = 0.f, d2 = 0.f;
    #pragma unroll
    for (int j = 0; j < 24; ++j) {
        float w = W_ar[q * 24 + j];
        d1 = fmaf(v1[j], w, d1);
        d2 = fmaf(v2[j], w, d2);
    }
    d1 += __shfl_xor(d1, 1); d1 += __shfl_xor(d1, 2);
    d2 += __shfl_xor(d2, 1); d2 += __shfl_xor(d2, 2);

    float n1 = norm1[n], n2 = norm2[n], aiv = ai[n], br = b_ar[0];
    float x1 = aiv + n1 * d1 + br;
    float x2 = aiv + n2 * d2 + br;
    float l1 = x1 >= 0.f ? x1 : 0.2f * x1;
    float l2 = x2 >= 0.f ? x2 : 0.2f * x2;
    float e1 = fminf(fmaxf(__expf(l1), -10.f), 10.f);
    float e2 = fminf(fmaxf(__expf(l2), -10.f), 10.f);
    float inv = 1.f / (e1 + e2);
    float s1 = e1 * inv * n1;
    float s2 = e2 * inv * n2;

    unsigned short ob[24];
    #pragma unroll
    for (int j = 0; j < 24; ++j)
        ob[j] = (unsigned short)f2bf(s1 * v1[j] + s2 * v2[j]);
    uint4* op = reinterpret_cast<uint4*>(combb + (size_t)n * HIDF + q * 24);
    const uint4* ip = reinterpret_cast<const uint4*>(ob);
    op[0] = ip[0]; op[1] = ip[1]; op[2] = ip[2];
}

// ---------- GEMM2 (R4-proven, verbatim) ----------
__global__ __launch_bounds__(256) void gemm_fc(
    const unsigned short* __restrict__ combb, const short* __restrict__ Bp2,
    const float* __restrict__ b_fc, float* __restrict__ out, int N)
{
    __shared__ short Bs[3 * 6 * 64 * 8];   // 18 KiB
    {
        const uint4* gsrc = reinterpret_cast<const uint4*>(Bp2);
        uint4* ldst = reinterpret_cast<uint4*>(Bs);
        for (int i = threadIdx.x; i < 3 * 6 * 64 * 8 / 8; i += 256) ldst[i] = gsrc[i];
    }
    __syncthreads();

    int lane = threadIdx.x & 63;
    int wid = threadIdx.x >> 6;
    int m0 = blockIdx.x * 64 + wid * 16;
    int arow = m0 + (lane & 15);
    int rc = arow < N ? arow : N - 1;
    const unsigned short* crow = combb + (size_t)rc * HIDF;
    int koff = (lane >> 4) << 3;

    f32x4 acc[6];
    #pragma unroll
    for (int nt = 0; nt < 6; ++nt) acc[nt] = (f32x4){0.f, 0.f, 0.f, 0.f};

    #pragma unroll
    for (int kt = 0; kt < 3; ++kt) {
        bf16x8 a8 = *reinterpret_cast<const bf16x8*>(crow + kt * 32 + koff);
        #pragma unroll
        for (int nt = 0; nt < 6; ++nt) {
            bf16x8 b8 = *reinterpret_cast<const bf16x8*>(&Bs[((kt * 6 + nt) * 64 + lane) * 8]);
            acc[nt] = __builtin_amdgcn_mfma_f32_16x16x32_bf16(a8, b8, acc[nt], 0, 0, 0);
        }
    }

    int rbase = m0 + ((lane >> 4) << 2);
    #pragma unroll
    for (int nt = 0; nt < 6; ++nt) {
        int col = nt * 16 + (lane & 15);
        float bf = b_fc[col];
        #pragma unroll
        for (int r = 0; r < 4; ++r) {
            int rrow = rbase + r;
            if (rrow < N) out[(size_t)rrow * HIDF + col] = acc[nt][r] + bf;
        }
    }
}

extern "C" void kernel_launch(void* const* d_in, const int* in_sizes, int n_in,
                              void* d_out, int out_size, void* d_ws, size_t ws_size,
                              hipStream_t stream) {
    const float* h     = (const float*)d_in[0];
    const float* norm1 = (const float*)d_in[1];
    const float* norm2 = (const float*)d_in[2];
    const int*   src1  = (const int*)d_in[3];
    const int*   dst1  = (const int*)d_in[4];
    const int*   src2  = (const int*)d_in[5];
    const int*   dst2  = (const int*)d_in[6];
    const float* W_lin = (const float*)d_in[7];
    const float* b_lin = (const float*)d_in[8];
    const float* W_fc  = (const float*)d_in[9];
    const float* b_fc  = (const float*)d_in[10];
    const float* W_al  = (const float*)d_in[11];
    const float* b_al  = (const float*)d_in[12];
    const float* W_ar  = (const float*)d_in[13];
    const float* b_ar  = (const float*)d_in[14];

    const int N = in_sizes[1];
    const int E = in_sizes[3];

    const int nb1  = (N + BK_SIZE - 1) >> BK_SHIFT;   // buckets per graph (1563)
    const int nbkt = 2 * nb1;                          // 3126
    const int nscan = nbkt * SCAT_NB;                  // 1600512
    const int nsb = (nscan + 2047) / 2048;             // 782 (<=1024 for scan_top)

    char* p = (char*)d_ws;
    auto alloc = [&](size_t bytes) {
        char* r = p;
        p += (bytes + 255) & ~(size_t)255;
        return r;
    };
    short* Bp1  = (short*)alloc((size_t)8 * 6 * 64 * 8 * 2);
    short* Bp2  = (short*)alloc((size_t)3 * 6 * 64 * 8 * 2);
    float* ai   = (float*)alloc((size_t)N * 4);
    unsigned short* linb  = (unsigned short*)alloc((size_t)N * HIDF * 2);
    unsigned short* combb = (unsigned short*)alloc((size_t)N * HIDF * 2);
    int*   hist_mat = (int*)alloc((size_t)nscan * 4);
    int*   payload  = (int*)alloc((size_t)2 * E * 4);
    int*   bsum     = (int*)alloc(1024 * 4);

    pack_weights<<<(8 * 6 * 64 + 3 * 6 * 64 + 255) / 256, 256, 0, stream>>>(W_lin, W_fc, Bp1, Bp2);

    bucket_hist<<<SCAT_NB, 256, 0, stream>>>(dst1, dst2, hist_mat, E, nb1, nbkt);
    scan_part8<<<nsb, 256, 0, stream>>>(hist_mat, bsum, nscan);
    scan_top<<<1, 1024, 0, stream>>>(bsum, nsb);
    scan_add8<<<nsb, 256, 0, stream>>>(hist_mat, bsum, nscan);
    bucket_scatter<<<SCAT_NB, 256, 0, stream>>>(
        src1, dst1, src2, dst2, hist_mat, payload, E, nb1, nbkt);

    int mblocks = (N + 63) / 64;
    gemm_lin<<<mblocks, 256, 0, stream>>>(h, Bp1, b_lin, W_al, b_al, linb, ai, N);

    agg_comb<<<nb1, 256, 0, stream>>>(
        linb, norm1, norm2, ai, W_ar, b_ar, hist_mat, payload, combb, N, nb1, nbkt, 2 * E);

    gemm_fc<<<mblocks, 256, 0, stream>>>(combb, Bp2, b_fc, (float*)d_out, N);
}

// Round 15
// 132.693 us; speedup vs baseline: 1.1461x; 1.1461x over previous
//
#include <hip/hip_runtime.h>
#include <hip/hip_bf16.h>

#define HIDF 96
#define INF 256
#define BK_SHIFT 5
#define BK_SIZE 32         // dst nodes per bucket
#define SCAT_NB 256        // blocks in hist/scatter pass (512 threads each)
#define MAX_BKT_E 1536     // bucket edge capacity (mean ~512, huge sigma headroom)

typedef short bf16x8 __attribute__((ext_vector_type(8)));
typedef float f32x4 __attribute__((ext_vector_type(4)));

static __device__ inline short f2bf(float f) {
    __hip_bfloat16 b = __float2bfloat16(f);
    short s;
    __builtin_memcpy(&s, &b, 2);
    return s;
}
static __device__ inline float bf2f(unsigned u) {
    union { unsigned x; float f; } v;
    v.x = u << 16;
    return v.f;
}

// ---------- pack W_lin and W_fc into MFMA B-fragment layout (R4-proven) ----------
__global__ __launch_bounds__(256) void pack_weights(
    const float* __restrict__ W_lin, const float* __restrict__ W_fc,
    short* __restrict__ Bp1, short* __restrict__ Bp2)
{
    int t = blockIdx.x * 256 + threadIdx.x;
    if (t < 8 * 6 * 64) {
        int kt = t / (6 * 64), rem = t % (6 * 64), nt = rem / 64, l = rem % 64;
        int n = nt * 16 + (l & 15);
        int k0 = kt * 32 + ((l >> 4) << 3);
        short v[8];
        #pragma unroll
        for (int j = 0; j < 8; ++j) v[j] = f2bf(W_lin[n * INF + k0 + j]);
        #pragma unroll
        for (int j = 0; j < 8; ++j) Bp1[(size_t)t * 8 + j] = v[j];
    } else if (t < 8 * 6 * 64 + 3 * 6 * 64) {
        int u = t - 8 * 6 * 64;
        int kt = u / (6 * 64), rem = u % (6 * 64), nt = rem / 64, l = rem % 64;
        int n = nt * 16 + (l & 15);
        int k0 = kt * 32 + ((l >> 4) << 3);
        short v[8];
        #pragma unroll
        for (int j = 0; j < 8; ++j) v[j] = f2bf(W_fc[n * HIDF + k0 + j]);
        #pragma unroll
        for (int j = 0; j < 8; ++j) Bp2[(size_t)u * 8 + j] = v[j];
    }
}

// ---------- pass 1: per-block bucket histogram (512 threads, LDS atomics only) ----------
__global__ __launch_bounds__(512) void bucket_hist(
    const int* __restrict__ dst1, const int* __restrict__ dst2,
    int* __restrict__ hist_mat, int E, int nb1, int nbkt)
{
    __shared__ int lh[4096];                 // nbkt = 3126 fits
    for (int i = threadIdx.x; i < nbkt; i += 512) lh[i] = 0;
    __syncthreads();
    int epb = (2 * E + SCAT_NB - 1) / SCAT_NB;
    int s0 = blockIdx.x * epb;
    int s1 = min(s0 + epb, 2 * E);
    for (int e = s0 + threadIdx.x; e < s1; e += 512) {
        int b;
        if (e < E) b = dst1[e] >> BK_SHIFT;
        else       b = nb1 + (dst2[e - E] >> BK_SHIFT);
        atomicAdd(&lh[b], 1);
    }
    __syncthreads();
    for (int i = threadIdx.x; i < nbkt; i += 512)
        hist_mat[(size_t)i * SCAT_NB + blockIdx.x] = lh[i];
}

// ---------- scan: 2048 elems/block, in-place exclusive ----------
__global__ __launch_bounds__(256) void scan_part8(
    int* __restrict__ data, int* __restrict__ bsum, int n)
{
    __shared__ int s[256];
    int base = blockIdx.x * 2048 + threadIdx.x * 8;
    int v[8]; int tot = 0;
    #pragma unroll
    for (int j = 0; j < 8; ++j) {
        v[j] = (base + j < n) ? data[base + j] : 0;
        tot += v[j];
    }
    s[threadIdx.x] = tot;
    __syncthreads();
    for (int d = 1; d < 256; d <<= 1) {
        int t = (threadIdx.x >= d) ? s[threadIdx.x - d] : 0;
        __syncthreads();
        s[threadIdx.x] += t;
        __syncthreads();
    }
    int pre = s[threadIdx.x] - tot;
    #pragma unroll
    for (int j = 0; j < 8; ++j) {
        if (base + j < n) data[base + j] = pre;
        pre += v[j];
    }
    if (threadIdx.x == 255) bsum[blockIdx.x] = s[255];
}

__global__ __launch_bounds__(1024) void scan_top(int* __restrict__ bsum, int nb)
{
    __shared__ int s[1024];
    int i = threadIdx.x;
    int v = (i < nb) ? bsum[i] : 0;
    s[i] = v;
    __syncthreads();
    for (int d = 1; d < 1024; d <<= 1) {
        int t = (i >= d) ? s[i - d] : 0;
        __syncthreads();
        s[i] += t;
        __syncthreads();
    }
    if (i < nb) bsum[i] = s[i] - v;
}

__global__ __launch_bounds__(256) void scan_add8(
    int* __restrict__ data, const int* __restrict__ bsum, int n)
{
    int base = blockIdx.x * 2048 + threadIdx.x * 8;
    int add = bsum[blockIdx.x];
    #pragma unroll
    for (int j = 0; j < 8; ++j)
        if (base + j < n) data[base + j] += add;
}

// ---------- pass 2: scatter edges into bucket-grouped payload (512 threads, LDS cursors) ----------
__global__ __launch_bounds__(512) void bucket_scatter(
    const int* __restrict__ src1, const int* __restrict__ dst1,
    const int* __restrict__ src2, const int* __restrict__ dst2,
    const int* __restrict__ hist_mat, int* __restrict__ payload,
    int E, int nb1, int nbkt)
{
    __shared__ int lcur[4096];
    for (int i = threadIdx.x; i < nbkt; i += 512)
        lcur[i] = hist_mat[(size_t)i * SCAT_NB + blockIdx.x];
    __syncthreads();
    int epb = (2 * E + SCAT_NB - 1) / SCAT_NB;
    int s0 = blockIdx.x * epb;
    int s1 = min(s0 + epb, 2 * E);
    for (int e = s0 + threadIdx.x; e < s1; e += 512) {
        int s, d, b;
        if (e < E) { s = src1[e]; d = dst1[e]; b = d >> BK_SHIFT; }
        else       { int e2 = e - E; s = src2[e2]; d = dst2[e2]; b = nb1 + (d >> BK_SHIFT); }
        int slot = atomicAdd(&lcur[b], 1);   // LDS atomic, cheap
        payload[slot] = ((d & (BK_SIZE - 1)) << 16) | s;   // src < 65536
    }
}

// ---------- GEMM1: K-split staging (R10-proven, unified linb) ----------
__global__ __launch_bounds__(256) void gemm_lin(
    const float* __restrict__ h, const short* __restrict__ Bp1,
    const float* __restrict__ b_lin, const float* __restrict__ W_al,
    const float* __restrict__ b_al,
    unsigned short* __restrict__ linb, float* __restrict__ ai, int N)
{
    __shared__ short Bs[4 * 6 * 64 * 8];   // 24 KiB (half the ktiles at a time)

    int lane = threadIdx.x & 63;
    int wid = threadIdx.x >> 6;
    int m0 = blockIdx.x * 64 + wid * 16;
    int arow = m0 + (lane & 15);
    int rc = arow < N ? arow : N - 1;
    const float* hrow = h + (size_t)rc * INF;
    int koff = (lane >> 4) << 3;

    f32x4 acc[6];
    #pragma unroll
    for (int nt = 0; nt < 6; ++nt) acc[nt] = (f32x4){0.f, 0.f, 0.f, 0.f};

    for (int half = 0; half < 2; ++half) {
        {
            const uint4* gsrc = reinterpret_cast<const uint4*>(Bp1) + (size_t)half * (4 * 6 * 64 * 8 / 8);
            uint4* ldst = reinterpret_cast<uint4*>(Bs);
            for (int i = threadIdx.x; i < 4 * 6 * 64 * 8 / 8; i += 256) ldst[i] = gsrc[i];
        }
        __syncthreads();

        #pragma unroll
        for (int kt = 0; kt < 4; ++kt) {
            int ktg = half * 4 + kt;
            const float4* hp = reinterpret_cast<const float4*>(hrow + ktg * 32 + koff);
            float4 f0 = hp[0], f1 = hp[1];
            bf16x8 a8;
            a8[0] = f2bf(f0.x); a8[1] = f2bf(f0.y); a8[2] = f2bf(f0.z); a8[3] = f2bf(f0.w);
            a8[4] = f2bf(f1.x); a8[5] = f2bf(f1.y); a8[6] = f2bf(f1.z); a8[7] = f2bf(f1.w);
            #pragma unroll
            for (int nt = 0; nt < 6; ++nt) {
                bf16x8 b8 = *reinterpret_cast<const bf16x8*>(&Bs[((kt * 6 + nt) * 64 + lane) * 8]);
                acc[nt] = __builtin_amdgcn_mfma_f32_16x16x32_bf16(a8, b8, acc[nt], 0, 0, 0);
            }
        }
        __syncthreads();
    }

    float pai[4] = {0.f, 0.f, 0.f, 0.f};
    int rbase = m0 + ((lane >> 4) << 2);
    #pragma unroll
    for (int nt = 0; nt < 6; ++nt) {
        int col = nt * 16 + (lane & 15);
        float bl = b_lin[col];
        float wal = W_al[col];
        #pragma unroll
        for (int r = 0; r < 4; ++r) {
            float v = acc[nt][r] + bl;
            int rrow = rbase + r;
            if (rrow < N) linb[(size_t)rrow * HIDF + col] = (unsigned short)f2bf(v);
            pai[r] = fmaf(wal, v, pai[r]);
        }
    }
    #pragma unroll
    for (int r = 0; r < 4; ++r) {
        float p = pai[r];
        p += __shfl_xor(p, 1);
        p += __shfl_xor(p, 2);
        p += __shfl_xor(p, 4);
        p += __shfl_xor(p, 8);
        int rrow = rbase + r;
        if ((lane & 15) == 0 && rrow < N) ai[rrow] = p + b_al[0];
    }
}

// ---------- agg+comb fused (BK=32, R14-proven): block b reduces bucket b (graph1) AND
//            bucket nb1+b (graph2) into LDS bf16 tiles, then attention-combine in-block ----------
__global__ __launch_bounds__(256) void agg_comb(
    const unsigned short* __restrict__ linb,
    const float* __restrict__ norm1, const float* __restrict__ norm2,
    const float* __restrict__ ai,
    const float* __restrict__ W_ar, const float* __restrict__ b_ar,
    const int* __restrict__ hist_mat, const int* __restrict__ payload,
    unsigned short* __restrict__ combb,
    int N, int nb1, int nbkt, int totE)
{
    __shared__ unsigned short srt[MAX_BKT_E];       // 3 KiB, reused across the two graphs
    __shared__ int scn[BK_SIZE];
    __shared__ int sstart[BK_SIZE + 1];
    __shared__ int cur[BK_SIZE];
    __shared__ unsigned short Cs[2][BK_SIZE][104];  // 13.3 KiB bf16 acc tiles

    int b = blockIdx.x;
    int node0 = b << BK_SHIFT;

    for (int gph = 0; gph < 2; ++gph) {
        int bidx = gph * nb1 + b;
        int start = hist_mat[(size_t)bidx * SCAT_NB];
        int end = (bidx == nbkt - 1) ? totE : hist_mat[(size_t)(bidx + 1) * SCAT_NB];
        if (end - start > MAX_BKT_E) end = start + MAX_BKT_E;   // safety clamp
        int ne = end - start;

        __syncthreads();   // protect srt/scn reuse from previous phase's readers
        if (threadIdx.x < BK_SIZE) scn[threadIdx.x] = 0;
        __syncthreads();

        // count per dst-local
        for (int k = start + threadIdx.x; k < end; k += 256)
            atomicAdd(&scn[payload[k] >> 16], 1);
        __syncthreads();

        // inclusive Hillis-Steele scan over 32 counters
        int v = (threadIdx.x < BK_SIZE) ? scn[threadIdx.x] : 0;
        for (int d = 1; d < BK_SIZE; d <<= 1) {
            int t = 0;
            if (threadIdx.x < BK_SIZE && threadIdx.x >= d) t = scn[threadIdx.x - d];
            __syncthreads();
            if (threadIdx.x < BK_SIZE) scn[threadIdx.x] += t;
            __syncthreads();
        }
        if (threadIdx.x < BK_SIZE) {
            int excl = scn[threadIdx.x] - v;
            sstart[threadIdx.x] = excl;
            cur[threadIdx.x] = excl;
        }
        if (threadIdx.x == 0) sstart[BK_SIZE] = ne;
        __syncthreads();

        // scatter srcs into dst-sorted LDS array
        for (int k = start + threadIdx.x; k < end; k += 256) {
            int pl = payload[k];
            int slot = atomicAdd(&cur[pl >> 16], 1);
            srt[slot] = (unsigned short)(pl & 0xffff);
        }
        __syncthreads();

        // segment reduction: 21 groups of 12 lanes, register accumulation, 4-deep gather ILP
        const float* nrm = gph ? norm2 : norm1;
        int g = threadIdx.x / 12;
        int c = threadIdx.x % 12;
        if (g < 21) {
            for (int dl = g; dl < BK_SIZE; dl += 21) {
                int node = node0 + dl;
                if (node >= N) break;
                int s0 = sstart[dl], s1 = sstart[dl + 1];
                float a[8];
                #pragma unroll
                for (int j = 0; j < 8; ++j) a[j] = 0.f;
                int k = s0;
                for (; k + 3 < s1; k += 4) {
                    int sA = srt[k], sB = srt[k + 1], sC = srt[k + 2], sD = srt[k + 3];
                    float nvA = nrm[sA], nvB = nrm[sB], nvC = nrm[sC], nvD = nrm[sD];
                    uint4 rA = *reinterpret_cast<const uint4*>(linb + (size_t)sA * HIDF + c * 8);
                    uint4 rB = *reinterpret_cast<const uint4*>(linb + (size_t)sB * HIDF + c * 8);
                    uint4 rC = *reinterpret_cast<const uint4*>(linb + (size_t)sC * HIDF + c * 8);
                    uint4 rD = *reinterpret_cast<const uint4*>(linb + (size_t)sD * HIDF + c * 8);
                    a[0] = fmaf(bf2f(rA.x & 0xffffu), nvA, a[0]);
                    a[1] = fmaf(bf2f(rA.x >> 16),     nvA, a[1]);
                    a[2] = fmaf(bf2f(rA.y & 0xffffu), nvA, a[2]);
                    a[3] = fmaf(bf2f(rA.y >> 16),     nvA, a[3]);
                    a[4] = fmaf(bf2f(rA.z & 0xffffu), nvA, a[4]);
                    a[5] = fmaf(bf2f(rA.z >> 16),     nvA, a[5]);
                    a[6] = fmaf(bf2f(rA.w & 0xffffu), nvA, a[6]);
                    a[7] = fmaf(bf2f(rA.w >> 16),     nvA, a[7]);
                    a[0] = fmaf(bf2f(rB.x & 0xffffu), nvB, a[0]);
                    a[1] = fmaf(bf2f(rB.x >> 16),     nvB, a[1]);
                    a[2] = fmaf(bf2f(rB.y & 0xffffu), nvB, a[2]);
                    a[3] = fmaf(bf2f(rB.y >> 16),     nvB, a[3]);
                    a[4] = fmaf(bf2f(rB.z & 0xffffu), nvB, a[4]);
                    a[5] = fmaf(bf2f(rB.z >> 16),     nvB, a[5]);
                    a[6] = fmaf(bf2f(rB.w & 0xffffu), nvB, a[6]);
                    a[7] = fmaf(bf2f(rB.w >> 16),     nvB, a[7]);
                    a[0] = fmaf(bf2f(rC.x & 0xffffu), nvC, a[0]);
                    a[1] = fmaf(bf2f(rC.x >> 16),     nvC, a[1]);
                    a[2] = fmaf(bf2f(rC.y & 0xffffu), nvC, a[2]);
                    a[3] = fmaf(bf2f(rC.y >> 16),     nvC, a[3]);
                    a[4] = fmaf(bf2f(rC.z & 0xffffu), nvC, a[4]);
                    a[5] = fmaf(bf2f(rC.z >> 16),     nvC, a[5]);
                    a[6] = fmaf(bf2f(rC.w & 0xffffu), nvC, a[6]);
                    a[7] = fmaf(bf2f(rC.w >> 16),     nvC, a[7]);
                    a[0] = fmaf(bf2f(rD.x & 0xffffu), nvD, a[0]);
                    a[1] = fmaf(bf2f(rD.x >> 16),     nvD, a[1]);
                    a[2] = fmaf(bf2f(rD.y & 0xffffu), nvD, a[2]);
                    a[3] = fmaf(bf2f(rD.y >> 16),     nvD, a[3]);
                    a[4] = fmaf(bf2f(rD.z & 0xffffu), nvD, a[4]);
                    a[5] = fmaf(bf2f(rD.z >> 16),     nvD, a[5]);
                    a[6] = fmaf(bf2f(rD.w & 0xffffu), nvD, a[6]);
                    a[7] = fmaf(bf2f(rD.w >> 16),     nvD, a[7]);
                }
                for (; k < s1; ++k) {
                    int s = srt[k];
                    float nv = nrm[s];
                    uint4 raw = *reinterpret_cast<const uint4*>(linb + (size_t)s * HIDF + c * 8);
                    a[0] = fmaf(bf2f(raw.x & 0xffffu), nv, a[0]);
                    a[1] = fmaf(bf2f(raw.x >> 16),     nv, a[1]);
                    a[2] = fmaf(bf2f(raw.y & 0xffffu), nv, a[2]);
                    a[3] = fmaf(bf2f(raw.y >> 16),     nv, a[3]);
                    a[4] = fmaf(bf2f(raw.z & 0xffffu), nv, a[4]);
                    a[5] = fmaf(bf2f(raw.z >> 16),     nv, a[5]);
                    a[6] = fmaf(bf2f(raw.w & 0xffffu), nv, a[6]);
                    a[7] = fmaf(bf2f(raw.w >> 16),     nv, a[7]);
                }
                unsigned ob[4];
                ob[0] = ((unsigned)(unsigned short)f2bf(a[1]) << 16) | (unsigned short)f2bf(a[0]);
                ob[1] = ((unsigned)(unsigned short)f2bf(a[3]) << 16) | (unsigned short)f2bf(a[2]);
                ob[2] = ((unsigned)(unsigned short)f2bf(a[5]) << 16) | (unsigned short)f2bf(a[4]);
                ob[3] = ((unsigned)(unsigned short)f2bf(a[7]) << 16) | (unsigned short)f2bf(a[6]);
                uint4 ov; ov.x = ob[0]; ov.y = ob[1]; ov.z = ob[2]; ov.w = ob[3];
                *reinterpret_cast<uint4*>(&Cs[gph][dl][c * 8]) = ov;
            }
        }
    }
    __syncthreads();

    // ---- comb phase (R12 comb_c1 logic, sourced from LDS tiles): 4 threads per node ----
    int nl = threadIdx.x >> 2, q = threadIdx.x & 3;
    if (nl >= BK_SIZE) return;
    int n = node0 + nl;
    if (n >= N) return;

    const uint4* r1 = reinterpret_cast<const uint4*>(&Cs[0][nl][q * 24]);
    const uint4* r2 = reinterpret_cast<const uint4*>(&Cs[1][nl][q * 24]);
    float v1[24], v2[24];
    #pragma unroll
    for (int u = 0; u < 3; ++u) {
        uint4 a = r1[u], bb = r2[u];
        v1[u*8+0] = bf2f(a.x & 0xffffu); v1[u*8+1] = bf2f(a.x >> 16);
        v1[u*8+2] = bf2f(a.y & 0xffffu); v1[u*8+3] = bf2f(a.y >> 16);
        v1[u*8+4] = bf2f(a.z & 0xffffu); v1[u*8+5] = bf2f(a.z >> 16);
        v1[u*8+6] = bf2f(a.w & 0xffffu); v1[u*8+7] = bf2f(a.w >> 16);
        v2[u*8+0] = bf2f(bb.x & 0xffffu); v2[u*8+1] = bf2f(bb.x >> 16);
        v2[u*8+2] = bf2f(bb.y & 0xffffu); v2[u*8+3] = bf2f(bb.y >> 16);
        v2[u*8+4] = bf2f(bb.z & 0xffffu); v2[u*8+5] = bf2f(bb.z >> 16);
        v2[u*8+6] = bf2f(bb.w & 0xffffu); v2[u*8+7] = bf2f(bb.w >> 16);
    }

    float d1 = 0.f, d2 = 0.f;
    #pragma unroll
    for (int j = 0; j < 24; ++j) {
        float w = W_ar[q * 24 + j];
        d1 = fmaf(v1[j], w, d1);
        d2 = fmaf(v2[j], w, d2);
    }
    d1 += __shfl_xor(d1, 1); d1 += __shfl_xor(d1, 2);
    d2 += __shfl_xor(d2, 1); d2 += __shfl_xor(d2, 2);

    float n1 = norm1[n], n2 = norm2[n], aiv = ai[n], br = b_ar[0];
    float x1 = aiv + n1 * d1 + br;
    float x2 = aiv + n2 * d2 + br;
    float l1 = x1 >= 0.f ? x1 : 0.2f * x1;
    float l2 = x2 >= 0.f ? x2 : 0.2f * x2;
    float e1 = fminf(fmaxf(__expf(l1), -10.f), 10.f);
    float e2 = fminf(fmaxf(__expf(l2), -10.f), 10.f);
    float inv = 1.f / (e1 + e2);
    float s1 = e1 * inv * n1;
    float s2 = e2 * inv * n2;

    unsigned short ob[24];
    #pragma unroll
    for (int j = 0; j < 24; ++j)
        ob[j] = (unsigned short)f2bf(s1 * v1[j] + s2 * v2[j]);
    uint4* op = reinterpret_cast<uint4*>(combb + (size_t)n * HIDF + q * 24);
    const uint4* ip = reinterpret_cast<const uint4*>(ob);
    op[0] = ip[0]; op[1] = ip[1]; op[2] = ip[2];
}

// ---------- GEMM2 (R4-proven, verbatim) ----------
__global__ __launch_bounds__(256) void gemm_fc(
    const unsigned short* __restrict__ combb, const short* __restrict__ Bp2,
    const float* __restrict__ b_fc, float* __restrict__ out, int N)
{
    __shared__ short Bs[3 * 6 * 64 * 8];   // 18 KiB
    {
        const uint4* gsrc = reinterpret_cast<const uint4*>(Bp2);
        uint4* ldst = reinterpret_cast<uint4*>(Bs);
        for (int i = threadIdx.x; i < 3 * 6 * 64 * 8 / 8; i += 256) ldst[i] = gsrc[i];
    }
    __syncthreads();

    int lane = threadIdx.x & 63;
    int wid = threadIdx.x >> 6;
    int m0 = blockIdx.x * 64 + wid * 16;
    int arow = m0 + (lane & 15);
    int rc = arow < N ? arow : N - 1;
    const unsigned short* crow = combb + (size_t)rc * HIDF;
    int koff = (lane >> 4) << 3;

    f32x4 acc[6];
    #pragma unroll
    for (int nt = 0; nt < 6; ++nt) acc[nt] = (f32x4){0.f, 0.f, 0.f, 0.f};

    #pragma unroll
    for (int kt = 0; kt < 3; ++kt) {
        bf16x8 a8 = *reinterpret_cast<const bf16x8*>(crow + kt * 32 + koff);
        #pragma unroll
        for (int nt = 0; nt < 6; ++nt) {
            bf16x8 b8 = *reinterpret_cast<const bf16x8*>(&Bs[((kt * 6 + nt) * 64 + lane) * 8]);
            acc[nt] = __builtin_amdgcn_mfma_f32_16x16x32_bf16(a8, b8, acc[nt], 0, 0, 0);
        }
    }

    int rbase = m0 + ((lane >> 4) << 2);
    #pragma unroll
    for (int nt = 0; nt < 6; ++nt) {
        int col = nt * 16 + (lane & 15);
        float bf = b_fc[col];
        #pragma unroll
        for (int r = 0; r < 4; ++r) {
            int rrow = rbase + r;
            if (rrow < N) out[(size_t)rrow * HIDF + col] = acc[nt][r] + bf;
        }
    }
}

extern "C" void kernel_launch(void* const* d_in, const int* in_sizes, int n_in,
                              void* d_out, int out_size, void* d_ws, size_t ws_size,
                              hipStream_t stream) {
    const float* h     = (const float*)d_in[0];
    const float* norm1 = (const float*)d_in[1];
    const float* norm2 = (const float*)d_in[2];
    const int*   src1  = (const int*)d_in[3];
    const int*   dst1  = (const int*)d_in[4];
    const int*   src2  = (const int*)d_in[5];
    const int*   dst2  = (const int*)d_in[6];
    const float* W_lin = (const float*)d_in[7];
    const float* b_lin = (const float*)d_in[8];
    const float* W_fc  = (const float*)d_in[9];
    const float* b_fc  = (const float*)d_in[10];
    const float* W_al  = (const float*)d_in[11];
    const float* b_al  = (const float*)d_in[12];
    const float* W_ar  = (const float*)d_in[13];
    const float* b_ar  = (const float*)d_in[14];

    const int N = in_sizes[1];
    const int E = in_sizes[3];

    const int nb1  = (N + BK_SIZE - 1) >> BK_SHIFT;   // buckets per graph (1563)
    const int nbkt = 2 * nb1;                          // 3126
    const int nscan = nbkt * SCAT_NB;                  // 800256
    const int nsb = (nscan + 2047) / 2048;             // 391 (<=1024 for scan_top)

    char* p = (char*)d_ws;
    auto alloc = [&](size_t bytes) {
        char* r = p;
        p += (bytes + 255) & ~(size_t)255;
        return r;
    };
    short* Bp1  = (short*)alloc((size_t)8 * 6 * 64 * 8 * 2);
    short* Bp2  = (short*)alloc((size_t)3 * 6 * 64 * 8 * 2);
    float* ai   = (float*)alloc((size_t)N * 4);
    unsigned short* linb  = (unsigned short*)alloc((size_t)N * HIDF * 2);
    unsigned short* combb = (unsigned short*)alloc((size_t)N * HIDF * 2);
    int*   hist_mat = (int*)alloc((size_t)nscan * 4);
    int*   payload  = (int*)alloc((size_t)2 * E * 4);
    int*   bsum     = (int*)alloc(1024 * 4);

    pack_weights<<<(8 * 6 * 64 + 3 * 6 * 64 + 255) / 256, 256, 0, stream>>>(W_lin, W_fc, Bp1, Bp2);

    bucket_hist<<<SCAT_NB, 512, 0, stream>>>(dst1, dst2, hist_mat, E, nb1, nbkt);
    scan_part8<<<nsb, 256, 0, stream>>>(hist_mat, bsum, nscan);
    scan_top<<<1, 1024, 0, stream>>>(bsum, nsb);
    scan_add8<<<nsb, 256, 0, stream>>>(hist_mat, bsum, nscan);
    bucket_scatter<<<SCAT_NB, 512, 0, stream>>>(
        src1, dst1, src2, dst2, hist_mat, payload, E, nb1, nbkt);

    int mblocks = (N + 63) / 64;
    gemm_lin<<<mblocks, 256, 0, stream>>>(h, Bp1, b_lin, W_al, b_al, linb, ai, N);

    agg_comb<<<nb1, 256, 0, stream>>>(
        linb, norm1, norm2, ai, W_ar, b_ar, hist_mat, payload, combb, N, nb1, nbkt, 2 * E);

    gemm_fc<<<mblocks, 256, 0, stream>>>(combb, Bp2, b_fc, (float*)d_out, N);
}

// Round 16
// 132.142 us; speedup vs baseline: 1.1508x; 1.0042x over previous
//
#include <hip/hip_runtime.h>
#include <hip/hip_bf16.h>

#define HIDF 96
#define INF 256
#define BK_SHIFT 5
#define BK_SIZE 32         // dst nodes per bucket
#define SCAT_NB 256        // blocks in hist/scatter pass (512 threads each)
#define MAX_BKT_E 1536     // bucket edge capacity (mean ~512, huge sigma headroom)

typedef short bf16x8 __attribute__((ext_vector_type(8)));
typedef float f32x4 __attribute__((ext_vector_type(4)));

static __device__ inline short f2bf(float f) {
    __hip_bfloat16 b = __float2bfloat16(f);
    short s;
    __builtin_memcpy(&s, &b, 2);
    return s;
}
static __device__ inline float bf2f(unsigned u) {
    union { unsigned x; float f; } v;
    v.x = u << 16;
    return v.f;
}

// ---------- pack W_lin and W_fc into MFMA B-fragment layout (R4-proven) ----------
__global__ __launch_bounds__(256) void pack_weights(
    const float* __restrict__ W_lin, const float* __restrict__ W_fc,
    short* __restrict__ Bp1, short* __restrict__ Bp2)
{
    int t = blockIdx.x * 256 + threadIdx.x;
    if (t < 8 * 6 * 64) {
        int kt = t / (6 * 64), rem = t % (6 * 64), nt = rem / 64, l = rem % 64;
        int n = nt * 16 + (l & 15);
        int k0 = kt * 32 + ((l >> 4) << 3);
        short v[8];
        #pragma unroll
        for (int j = 0; j < 8; ++j) v[j] = f2bf(W_lin[n * INF + k0 + j]);
        #pragma unroll
        for (int j = 0; j < 8; ++j) Bp1[(size_t)t * 8 + j] = v[j];
    } else if (t < 8 * 6 * 64 + 3 * 6 * 64) {
        int u = t - 8 * 6 * 64;
        int kt = u / (6 * 64), rem = u % (6 * 64), nt = rem / 64, l = rem % 64;
        int n = nt * 16 + (l & 15);
        int k0 = kt * 32 + ((l >> 4) << 3);
        short v[8];
        #pragma unroll
        for (int j = 0; j < 8; ++j) v[j] = f2bf(W_fc[n * HIDF + k0 + j]);
        #pragma unroll
        for (int j = 0; j < 8; ++j) Bp2[(size_t)u * 8 + j] = v[j];
    }
}

// ---------- pass 1: per-block bucket histogram (512 threads, LDS atomics only) ----------
__global__ __launch_bounds__(512) void bucket_hist(
    const int* __restrict__ dst1, const int* __restrict__ dst2,
    int* __restrict__ hist_mat, int E, int nb1, int nbkt)
{
    __shared__ int lh[4096];                 // nbkt = 3126 fits
    for (int i = threadIdx.x; i < nbkt; i += 512) lh[i] = 0;
    __syncthreads();
    int epb = (2 * E + SCAT_NB - 1) / SCAT_NB;
    int s0 = blockIdx.x * epb;
    int s1 = min(s0 + epb, 2 * E);
    for (int e = s0 + threadIdx.x; e < s1; e += 512) {
        int b;
        if (e < E) b = dst1[e] >> BK_SHIFT;
        else       b = nb1 + (dst2[e - E] >> BK_SHIFT);
        atomicAdd(&lh[b], 1);
    }
    __syncthreads();
    for (int i = threadIdx.x; i < nbkt; i += 512)
        hist_mat[(size_t)i * SCAT_NB + blockIdx.x] = lh[i];
}

// ---------- scan: 2048 elems/block, in-place exclusive ----------
__global__ __launch_bounds__(256) void scan_part8(
    int* __restrict__ data, int* __restrict__ bsum, int n)
{
    __shared__ int s[256];
    int base = blockIdx.x * 2048 + threadIdx.x * 8;
    int v[8]; int tot = 0;
    #pragma unroll
    for (int j = 0; j < 8; ++j) {
        v[j] = (base + j < n) ? data[base + j] : 0;
        tot += v[j];
    }
    s[threadIdx.x] = tot;
    __syncthreads();
    for (int d = 1; d < 256; d <<= 1) {
        int t = (threadIdx.x >= d) ? s[threadIdx.x - d] : 0;
        __syncthreads();
        s[threadIdx.x] += t;
        __syncthreads();
    }
    int pre = s[threadIdx.x] - tot;
    #pragma unroll
    for (int j = 0; j < 8; ++j) {
        if (base + j < n) data[base + j] = pre;
        pre += v[j];
    }
    if (threadIdx.x == 255) bsum[blockIdx.x] = s[255];
}

__global__ __launch_bounds__(1024) void scan_top(int* __restrict__ bsum, int nb)
{
    __shared__ int s[1024];
    int i = threadIdx.x;
    int v = (i < nb) ? bsum[i] : 0;
    s[i] = v;
    __syncthreads();
    for (int d = 1; d < 1024; d <<= 1) {
        int t = (i >= d) ? s[i - d] : 0;
        __syncthreads();
        s[i] += t;
        __syncthreads();
    }
    if (i < nb) bsum[i] = s[i] - v;
}

__global__ __launch_bounds__(256) void scan_add8(
    int* __restrict__ data, const int* __restrict__ bsum, int n)
{
    int base = blockIdx.x * 2048 + threadIdx.x * 8;
    int add = bsum[blockIdx.x];
    #pragma unroll
    for (int j = 0; j < 8; ++j)
        if (base + j < n) data[base + j] += add;
}

// ---------- pass 2: scatter edges into bucket-grouped payload (512 threads, LDS cursors) ----------
__global__ __launch_bounds__(512) void bucket_scatter(
    const int* __restrict__ src1, const int* __restrict__ dst1,
    const int* __restrict__ src2, const int* __restrict__ dst2,
    const int* __restrict__ hist_mat, int* __restrict__ payload,
    int E, int nb1, int nbkt)
{
    __shared__ int lcur[4096];
    for (int i = threadIdx.x; i < nbkt; i += 512)
        lcur[i] = hist_mat[(size_t)i * SCAT_NB + blockIdx.x];
    __syncthreads();
    int epb = (2 * E + SCAT_NB - 1) / SCAT_NB;
    int s0 = blockIdx.x * epb;
    int s1 = min(s0 + epb, 2 * E);
    for (int e = s0 + threadIdx.x; e < s1; e += 512) {
        int s, d, b;
        if (e < E) { s = src1[e]; d = dst1[e]; b = d >> BK_SHIFT; }
        else       { int e2 = e - E; s = src2[e2]; d = dst2[e2]; b = nb1 + (d >> BK_SHIFT); }
        int slot = atomicAdd(&lcur[b], 1);   // LDS atomic, cheap
        payload[slot] = ((d & (BK_SIZE - 1)) << 16) | s;   // src < 65536
    }
}

// ---------- GEMM1: K-split staging (R10-proven, unified linb) ----------
__global__ __launch_bounds__(256) void gemm_lin(
    const float* __restrict__ h, const short* __restrict__ Bp1,
    const float* __restrict__ b_lin, const float* __restrict__ W_al,
    const float* __restrict__ b_al,
    unsigned short* __restrict__ linb, float* __restrict__ ai, int N)
{
    __shared__ short Bs[4 * 6 * 64 * 8];   // 24 KiB (half the ktiles at a time)

    int lane = threadIdx.x & 63;
    int wid = threadIdx.x >> 6;
    int m0 = blockIdx.x * 64 + wid * 16;
    int arow = m0 + (lane & 15);
    int rc = arow < N ? arow : N - 1;
    const float* hrow = h + (size_t)rc * INF;
    int koff = (lane >> 4) << 3;

    f32x4 acc[6];
    #pragma unroll
    for (int nt = 0; nt < 6; ++nt) acc[nt] = (f32x4){0.f, 0.f, 0.f, 0.f};

    for (int half = 0; half < 2; ++half) {
        {
            const uint4* gsrc = reinterpret_cast<const uint4*>(Bp1) + (size_t)half * (4 * 6 * 64 * 8 / 8);
            uint4* ldst = reinterpret_cast<uint4*>(Bs);
            for (int i = threadIdx.x; i < 4 * 6 * 64 * 8 / 8; i += 256) ldst[i] = gsrc[i];
        }
        __syncthreads();

        #pragma unroll
        for (int kt = 0; kt < 4; ++kt) {
            int ktg = half * 4 + kt;
            const float4* hp = reinterpret_cast<const float4*>(hrow + ktg * 32 + koff);
            float4 f0 = hp[0], f1 = hp[1];
            bf16x8 a8;
            a8[0] = f2bf(f0.x); a8[1] = f2bf(f0.y); a8[2] = f2bf(f0.z); a8[3] = f2bf(f0.w);
            a8[4] = f2bf(f1.x); a8[5] = f2bf(f1.y); a8[6] = f2bf(f1.z); a8[7] = f2bf(f1.w);
            #pragma unroll
            for (int nt = 0; nt < 6; ++nt) {
                bf16x8 b8 = *reinterpret_cast<const bf16x8*>(&Bs[((kt * 6 + nt) * 64 + lane) * 8]);
                acc[nt] = __builtin_amdgcn_mfma_f32_16x16x32_bf16(a8, b8, acc[nt], 0, 0, 0);
            }
        }
        __syncthreads();
    }

    float pai[4] = {0.f, 0.f, 0.f, 0.f};
    int rbase = m0 + ((lane >> 4) << 2);
    #pragma unroll
    for (int nt = 0; nt < 6; ++nt) {
        int col = nt * 16 + (lane & 15);
        float bl = b_lin[col];
        float wal = W_al[col];
        #pragma unroll
        for (int r = 0; r < 4; ++r) {
            float v = acc[nt][r] + bl;
            int rrow = rbase + r;
            if (rrow < N) linb[(size_t)rrow * HIDF + col] = (unsigned short)f2bf(v);
            pai[r] = fmaf(wal, v, pai[r]);
        }
    }
    #pragma unroll
    for (int r = 0; r < 4; ++r) {
        float p = pai[r];
        p += __shfl_xor(p, 1);
        p += __shfl_xor(p, 2);
        p += __shfl_xor(p, 4);
        p += __shfl_xor(p, 8);
        int rrow = rbase + r;
        if ((lane & 15) == 0 && rrow < N) ai[rrow] = p + b_al[0];
    }
}

// ---------- agg+comb fused, 512 threads: the two graphs' buckets are sorted by
//            parallel 256-thread halves (shared barriers), then a unified 42-group
//            gather phase sweeps all 64 segments; comb runs in-block ----------
__global__ __launch_bounds__(512) void agg_comb(
    const unsigned short* __restrict__ linb,
    const float* __restrict__ norm1, const float* __restrict__ norm2,
    const float* __restrict__ ai,
    const float* __restrict__ W_ar, const float* __restrict__ b_ar,
    const int* __restrict__ hist_mat, const int* __restrict__ payload,
    unsigned short* __restrict__ combb,
    int N, int nb1, int nbkt, int totE)
{
    __shared__ unsigned short srt[2][MAX_BKT_E];    // 6 KiB
    __shared__ int scn[2][BK_SIZE];
    __shared__ int sstart[2][BK_SIZE + 1];
    __shared__ int cur[2][BK_SIZE];
    __shared__ unsigned short Cs[2][BK_SIZE][104];  // 13.3 KiB bf16 acc tiles

    int b = blockIdx.x;
    int node0 = b << BK_SHIFT;
    int wh = threadIdx.x >> 8;          // graph half: 0 or 1
    int tid = threadIdx.x & 255;

    // ---- parallel sort of both graph buckets (shared barrier structure) ----
    int bidx = wh * nb1 + b;
    int start = hist_mat[(size_t)bidx * SCAT_NB];
    int end = (bidx == nbkt - 1) ? totE : hist_mat[(size_t)(bidx + 1) * SCAT_NB];
    if (end - start > MAX_BKT_E) end = start + MAX_BKT_E;   // safety clamp
    int ne = end - start;

    if (tid < BK_SIZE) scn[wh][tid] = 0;
    __syncthreads();

    // count per dst-local
    for (int k = start + tid; k < end; k += 256)
        atomicAdd(&scn[wh][payload[k] >> 16], 1);
    __syncthreads();

    // inclusive Hillis-Steele scan over 32 counters (per half)
    int v = (tid < BK_SIZE) ? scn[wh][tid] : 0;
    for (int d = 1; d < BK_SIZE; d <<= 1) {
        int t = 0;
        if (tid < BK_SIZE && tid >= d) t = scn[wh][tid - d];
        __syncthreads();
        if (tid < BK_SIZE) scn[wh][tid] += t;
        __syncthreads();
    }
    if (tid < BK_SIZE) {
        int excl = scn[wh][tid] - v;
        sstart[wh][tid] = excl;
        cur[wh][tid] = excl;
    }
    if (tid == 0) sstart[wh][BK_SIZE] = ne;
    __syncthreads();

    // scatter srcs into dst-sorted LDS array
    for (int k = start + tid; k < end; k += 256) {
        int pl = payload[k];
        int slot = atomicAdd(&cur[wh][pl >> 16], 1);
        srt[wh][slot] = (unsigned short)(pl & 0xffff);
    }
    __syncthreads();

    // ---- unified gather: 42 groups of 12 lanes sweep 64 (wh,dl) segments ----
    int g = threadIdx.x / 12;
    int c = threadIdx.x % 12;
    if (g < 42) {
        for (int idx = g; idx < 2 * BK_SIZE; idx += 42) {
            int gw = idx >> BK_SHIFT;       // which graph
            int dl = idx & (BK_SIZE - 1);
            int node = node0 + dl;
            if (node >= N) continue;
            const float* nrm = gw ? norm2 : norm1;
            int s0 = sstart[gw][dl], s1 = sstart[gw][dl + 1];
            float a[8];
            #pragma unroll
            for (int j = 0; j < 8; ++j) a[j] = 0.f;
            int k = s0;
            for (; k + 3 < s1; k += 4) {
                int sA = srt[gw][k], sB = srt[gw][k + 1], sC = srt[gw][k + 2], sD = srt[gw][k + 3];
                float nvA = nrm[sA], nvB = nrm[sB], nvC = nrm[sC], nvD = nrm[sD];
                uint4 rA = *reinterpret_cast<const uint4*>(linb + (size_t)sA * HIDF + c * 8);
                uint4 rB = *reinterpret_cast<const uint4*>(linb + (size_t)sB * HIDF + c * 8);
                uint4 rC = *reinterpret_cast<const uint4*>(linb + (size_t)sC * HIDF + c * 8);
                uint4 rD = *reinterpret_cast<const uint4*>(linb + (size_t)sD * HIDF + c * 8);
                a[0] = fmaf(bf2f(rA.x & 0xffffu), nvA, a[0]);
                a[1] = fmaf(bf2f(rA.x >> 16),     nvA, a[1]);
                a[2] = fmaf(bf2f(rA.y & 0xffffu), nvA, a[2]);
                a[3] = fmaf(bf2f(rA.y >> 16),     nvA, a[3]);
                a[4] = fmaf(bf2f(rA.z & 0xffffu), nvA, a[4]);
                a[5] = fmaf(bf2f(rA.z >> 16),     nvA, a[5]);
                a[6] = fmaf(bf2f(rA.w & 0xffffu), nvA, a[6]);
                a[7] = fmaf(bf2f(rA.w >> 16),     nvA, a[7]);
                a[0] = fmaf(bf2f(rB.x & 0xffffu), nvB, a[0]);
                a[1] = fmaf(bf2f(rB.x >> 16),     nvB, a[1]);
                a[2] = fmaf(bf2f(rB.y & 0xffffu), nvB, a[2]);
                a[3] = fmaf(bf2f(rB.y >> 16),     nvB, a[3]);
                a[4] = fmaf(bf2f(rB.z & 0xffffu), nvB, a[4]);
                a[5] = fmaf(bf2f(rB.z >> 16),     nvB, a[5]);
                a[6] = fmaf(bf2f(rB.w & 0xffffu), nvB, a[6]);
                a[7] = fmaf(bf2f(rB.w >> 16),     nvB, a[7]);
                a[0] = fmaf(bf2f(rC.x & 0xffffu), nvC, a[0]);
                a[1] = fmaf(bf2f(rC.x >> 16),     nvC, a[1]);
                a[2] = fmaf(bf2f(rC.y & 0xffffu), nvC, a[2]);
                a[3] = fmaf(bf2f(rC.y >> 16),     nvC, a[3]);
                a[4] = fmaf(bf2f(rC.z & 0xffffu), nvC, a[4]);
                a[5] = fmaf(bf2f(rC.z >> 16),     nvC, a[5]);
                a[6] = fmaf(bf2f(rC.w & 0xffffu), nvC, a[6]);
                a[7] = fmaf(bf2f(rC.w >> 16),     nvC, a[7]);
                a[0] = fmaf(bf2f(rD.x & 0xffffu), nvD, a[0]);
                a[1] = fmaf(bf2f(rD.x >> 16),     nvD, a[1]);
                a[2] = fmaf(bf2f(rD.y & 0xffffu), nvD, a[2]);
                a[3] = fmaf(bf2f(rD.y >> 16),     nvD, a[3]);
                a[4] = fmaf(bf2f(rD.z & 0xffffu), nvD, a[4]);
                a[5] = fmaf(bf2f(rD.z >> 16),     nvD, a[5]);
                a[6] = fmaf(bf2f(rD.w & 0xffffu), nvD, a[6]);
                a[7] = fmaf(bf2f(rD.w >> 16),     nvD, a[7]);
            }
            for (; k < s1; ++k) {
                int s = srt[gw][k];
                float nv = nrm[s];
                uint4 raw = *reinterpret_cast<const uint4*>(linb + (size_t)s * HIDF + c * 8);
                a[0] = fmaf(bf2f(raw.x & 0xffffu), nv, a[0]);
                a[1] = fmaf(bf2f(raw.x >> 16),     nv, a[1]);
                a[2] = fmaf(bf2f(raw.y & 0xffffu), nv, a[2]);
                a[3] = fmaf(bf2f(raw.y >> 16),     nv, a[3]);
                a[4] = fmaf(bf2f(raw.z & 0xffffu), nv, a[4]);
                a[5] = fmaf(bf2f(raw.z >> 16),     nv, a[5]);
                a[6] = fmaf(bf2f(raw.w & 0xffffu), nv, a[6]);
                a[7] = fmaf(bf2f(raw.w >> 16),     nv, a[7]);
            }
            unsigned ob[4];
            ob[0] = ((unsigned)(unsigned short)f2bf(a[1]) << 16) | (unsigned short)f2bf(a[0]);
            ob[1] = ((unsigned)(unsigned short)f2bf(a[3]) << 16) | (unsigned short)f2bf(a[2]);
            ob[2] = ((unsigned)(unsigned short)f2bf(a[5]) << 16) | (unsigned short)f2bf(a[4]);
            ob[3] = ((unsigned)(unsigned short)f2bf(a[7]) << 16) | (unsigned short)f2bf(a[6]);
            uint4 ov; ov.x = ob[0]; ov.y = ob[1]; ov.z = ob[2]; ov.w = ob[3];
            *reinterpret_cast<uint4*>(&Cs[gw][dl][c * 8]) = ov;
        }
    }
    __syncthreads();

    // ---- comb phase (first 128 threads): 4 threads per node ----
    if (threadIdx.x >= 4 * BK_SIZE) return;
    int nl = threadIdx.x >> 2, q = threadIdx.x & 3;
    int n = node0 + nl;
    if (n >= N) return;

    const uint4* r1 = reinterpret_cast<const uint4*>(&Cs[0][nl][q * 24]);
    const uint4* r2 = reinterpret_cast<const uint4*>(&Cs[1][nl][q * 24]);
    float v1[24], v2[24];
    #pragma unroll
    for (int u = 0; u < 3; ++u) {
        uint4 a = r1[u], bb = r2[u];
        v1[u*8+0] = bf2f(a.x & 0xffffu); v1[u*8+1] = bf2f(a.x >> 16);
        v1[u*8+2] = bf2f(a.y & 0xffffu); v1[u*8+3] = bf2f(a.y >> 16);
        v1[u*8+4] = bf2f(a.z & 0xffffu); v1[u*8+5] = bf2f(a.z >> 16);
        v1[u*8+6] = bf2f(a.w & 0xffffu); v1[u*8+7] = bf2f(a.w >> 16);
        v2[u*8+0] = bf2f(bb.x & 0xffffu); v2[u*8+1] = bf2f(bb.x >> 16);
        v2[u*8+2] = bf2f(bb.y & 0xffffu); v2[u*8+3] = bf2f(bb.y >> 16);
        v2[u*8+4] = bf2f(bb.z & 0xffffu); v2[u*8+5] = bf2f(bb.z >> 16);
        v2[u*8+6] = bf2f(bb.w & 0xffffu); v2[u*8+7] = bf2f(bb.w >> 16);
    }

    float d1 = 0.f, d2 = 0.f;
    #pragma unroll
    for (int j = 0; j < 24; ++j) {
        float w = W_ar[q * 24 + j];
        d1 = fmaf(v1[j], w, d1);
        d2 = fmaf(v2[j], w, d2);
    }
    d1 += __shfl_xor(d1, 1); d1 += __shfl_xor(d1, 2);
    d2 += __shfl_xor(d2, 1); d2 += __shfl_xor(d2, 2);

    float n1 = norm1[n], n2 = norm2[n], aiv = ai[n], br = b_ar[0];
    float x1 = aiv + n1 * d1 + br;
    float x2 = aiv + n2 * d2 + br;
    float l1 = x1 >= 0.f ? x1 : 0.2f * x1;
    float l2 = x2 >= 0.f ? x2 : 0.2f * x2;
    float e1 = fminf(fmaxf(__expf(l1), -10.f), 10.f);
    float e2 = fminf(fmaxf(__expf(l2), -10.f), 10.f);
    float inv = 1.f / (e1 + e2);
    float s1 = e1 * inv * n1;
    float s2 = e2 * inv * n2;

    unsigned short ob[24];
    #pragma unroll
    for (int j = 0; j < 24; ++j)
        ob[j] = (unsigned short)f2bf(s1 * v1[j] + s2 * v2[j]);
    uint4* op = reinterpret_cast<uint4*>(combb + (size_t)n * HIDF + q * 24);
    const uint4* ip = reinterpret_cast<const uint4*>(ob);
    op[0] = ip[0]; op[1] = ip[1]; op[2] = ip[2];
}

// ---------- GEMM2 (R4-proven, verbatim) ----------
__global__ __launch_bounds__(256) void gemm_fc(
    const unsigned short* __restrict__ combb, const short* __restrict__ Bp2,
    const float* __restrict__ b_fc, float* __restrict__ out, int N)
{
    __shared__ short Bs[3 * 6 * 64 * 8];   // 18 KiB
    {
        const uint4* gsrc = reinterpret_cast<const uint4*>(Bp2);
        uint4* ldst = reinterpret_cast<uint4*>(Bs);
        for (int i = threadIdx.x; i < 3 * 6 * 64 * 8 / 8; i += 256) ldst[i] = gsrc[i];
    }
    __syncthreads();

    int lane = threadIdx.x & 63;
    int wid = threadIdx.x >> 6;
    int m0 = blockIdx.x * 64 + wid * 16;
    int arow = m0 + (lane & 15);
    int rc = arow < N ? arow : N - 1;
    const unsigned short* crow = combb + (size_t)rc * HIDF;
    int koff = (lane >> 4) << 3;

    f32x4 acc[6];
    #pragma unroll
    for (int nt = 0; nt < 6; ++nt) acc[nt] = (f32x4){0.f, 0.f, 0.f, 0.f};

    #pragma unroll
    for (int kt = 0; kt < 3; ++kt) {
        bf16x8 a8 = *reinterpret_cast<const bf16x8*>(crow + kt * 32 + koff);
        #pragma unroll
        for (int nt = 0; nt < 6; ++nt) {
            bf16x8 b8 = *reinterpret_cast<const bf16x8*>(&Bs[((kt * 6 + nt) * 64 + lane) * 8]);
            acc[nt] = __builtin_amdgcn_mfma_f32_16x16x32_bf16(a8, b8, acc[nt], 0, 0, 0);
        }
    }

    int rbase = m0 + ((lane >> 4) << 2);
    #pragma unroll
    for (int nt = 0; nt < 6; ++nt) {
        int col = nt * 16 + (lane & 15);
        float bf = b_fc[col];
        #pragma unroll
        for (int r = 0; r < 4; ++r) {
            int rrow = rbase + r;
            if (rrow < N) out[(size_t)rrow * HIDF + col] = acc[nt][r] + bf;
        }
    }
}

extern "C" void kernel_launch(void* const* d_in, const int* in_sizes, int n_in,
                              void* d_out, int out_size, void* d_ws, size_t ws_size,
                              hipStream_t stream) {
    const float* h     = (const float*)d_in[0];
    const float* norm1 = (const float*)d_in[1];
    const float* norm2 = (const float*)d_in[2];
    const int*   src1  = (const int*)d_in[3];
    const int*   dst1  = (const int*)d_in[4];
    const int*   src2  = (const int*)d_in[5];
    const int*   dst2  = (const int*)d_in[6];
    const float* W_lin = (const float*)d_in[7];
    const float* b_lin = (const float*)d_in[8];
    const float* W_fc  = (const float*)d_in[9];
    const float* b_fc  = (const float*)d_in[10];
    const float* W_al  = (const float*)d_in[11];
    const float* b_al  = (const float*)d_in[12];
    const float* W_ar  = (const float*)d_in[13];
    const float* b_ar  = (const float*)d_in[14];

    const int N = in_sizes[1];
    const int E = in_sizes[3];

    const int nb1  = (N + BK_SIZE - 1) >> BK_SHIFT;   // buckets per graph (1563)
    const int nbkt = 2 * nb1;                          // 3126
    const int nscan = nbkt * SCAT_NB;                  // 800256
    const int nsb = (nscan + 2047) / 2048;             // 391 (<=1024 for scan_top)

    char* p = (char*)d_ws;
    auto alloc = [&](size_t bytes) {
        char* r = p;
        p += (bytes + 255) & ~(size_t)255;
        return r;
    };
    short* Bp1  = (short*)alloc((size_t)8 * 6 * 64 * 8 * 2);
    short* Bp2  = (short*)alloc((size_t)3 * 6 * 64 * 8 * 2);
    float* ai   = (float*)alloc((size_t)N * 4);
    unsigned short* linb  = (unsigned short*)alloc((size_t)N * HIDF * 2);
    unsigned short* combb = (unsigned short*)alloc((size_t)N * HIDF * 2);
    int*   hist_mat = (int*)alloc((size_t)nscan * 4);
    int*   payload  = (int*)alloc((size_t)2 * E * 4);
    int*   bsum     = (int*)alloc(1024 * 4);

    pack_weights<<<(8 * 6 * 64 + 3 * 6 * 64 + 255) / 256, 256, 0, stream>>>(W_lin, W_fc, Bp1, Bp2);

    bucket_hist<<<SCAT_NB, 512, 0, stream>>>(dst1, dst2, hist_mat, E, nb1, nbkt);
    scan_part8<<<nsb, 256, 0, stream>>>(hist_mat, bsum, nscan);
    scan_top<<<1, 1024, 0, stream>>>(bsum, nsb);
    scan_add8<<<nsb, 256, 0, stream>>>(hist_mat, bsum, nscan);
    bucket_scatter<<<SCAT_NB, 512, 0, stream>>>(
        src1, dst1, src2, dst2, hist_mat, payload, E, nb1, nbkt);

    int mblocks = (N + 63) / 64;
    gemm_lin<<<mblocks, 256, 0, stream>>>(h, Bp1, b_lin, W_al, b_al, linb, ai, N);

    agg_comb<<<nb1, 512, 0, stream>>>(
        linb, norm1, norm2, ai, W_ar, b_ar, hist_mat, payload, combb, N, nb1, nbkt, 2 * E);

    gemm_fc<<<mblocks, 256, 0, stream>>>(combb, Bp2, b_fc, (float*)d_out, N);
}